// Round 1
// baseline (85.808 us; speedup 1.0000x reference)
//
#include <hip/hip_runtime.h>

// L0ConjunctionLayer: out[b,o] = prod_i (1 - (1 - x[b,i]*z[i]) * w[i,o])
// z[i] = clamp(sigmoid(qz_loga[i]) * 1.2 - 0.1, 0, 1)
// B=2048, I=512, O=256, all fp32.
//
// VALU-bound product-reduction GEMM. 32x32 output tile per block, BK=32,
// 256 threads, 2x2 register tile/thread -> 512 blocks = 2 blocks/CU =
// 8 waves/CU (2/SIMD) for latency hiding. LDS tiles padded to stride 34
// (2-way bank aliasing = free on gfx950).

#define DIM_B 2048
#define DIM_I 512
#define DIM_O 256
#define TILE_B 32
#define TILE_O 32
#define BK 32
#define LDS_STRIDE 34  // floats; +2 pad keeps 8B alignment for b64, 2-way banks max

__global__ __launch_bounds__(256) void l0conj_kernel(
    const float* __restrict__ x,      // [B, I]
    const float* __restrict__ w,      // [I, O]
    const float* __restrict__ qz,     // [I]
    float* __restrict__ out)          // [B, O]
{
    __shared__ float zS[DIM_I];
    __shared__ float yS[BK * LDS_STRIDE];  // [k][b], k-major, transposed
    __shared__ float wS[BK * LDS_STRIDE];  // [k][o], k-major

    const int t = threadIdx.x;
    const int bBase = blockIdx.x * TILE_B;
    const int oBase = blockIdx.y * TILE_O;

    // Per-block gate precompute: z[i] for all I (2 per thread).
    for (int i = t; i < DIM_I; i += 256) {
        float q = qz[i];
        float sig = 1.0f / (1.0f + __expf(-q));
        float z = fmaf(sig, 1.2f, -0.1f);
        zS[i] = fminf(fmaxf(z, 0.0f), 1.0f);
    }
    __syncthreads();

    // Staging thread mapping: row = t>>3 (0..31), quad = (t&7)*4 (0..28)
    const int ldRow = t >> 3;
    const int ldQuad = (t & 7) * 4;
    // Compute thread mapping: tx = o-pair (0..15), ty = b-pair (0..15)
    const int tx = t & 15;
    const int ty = t >> 4;

    float acc00 = 1.0f, acc01 = 1.0f, acc10 = 1.0f, acc11 = 1.0f;

    for (int k0 = 0; k0 < DIM_I; k0 += BK) {
        // Stage x-tile -> y = 1 - x*z, transposed into yS[k][b].
        const float4 xv = *(const float4*)(&x[(bBase + ldRow) * DIM_I + k0 + ldQuad]);
        const float z0 = zS[k0 + ldQuad + 0];
        const float z1 = zS[k0 + ldQuad + 1];
        const float z2 = zS[k0 + ldQuad + 2];
        const float z3 = zS[k0 + ldQuad + 3];
        yS[(ldQuad + 0) * LDS_STRIDE + ldRow] = fmaf(-xv.x, z0, 1.0f);
        yS[(ldQuad + 1) * LDS_STRIDE + ldRow] = fmaf(-xv.y, z1, 1.0f);
        yS[(ldQuad + 2) * LDS_STRIDE + ldRow] = fmaf(-xv.z, z2, 1.0f);
        yS[(ldQuad + 3) * LDS_STRIDE + ldRow] = fmaf(-xv.w, z3, 1.0f);

        // Stage w-tile into wS[k][o] (k-major, o contiguous). 2x b64 writes.
        const float4 wv = *(const float4*)(&w[(k0 + ldRow) * DIM_O + oBase + ldQuad]);
        *(float2*)(&wS[ldRow * LDS_STRIDE + ldQuad]) = make_float2(wv.x, wv.y);
        *(float2*)(&wS[ldRow * LDS_STRIDE + ldQuad + 2]) = make_float2(wv.z, wv.w);

        __syncthreads();

        #pragma unroll
        for (int k = 0; k < BK; ++k) {
            const float2 yv = *(const float2*)(&yS[k * LDS_STRIDE + 2 * ty]);
            const float2 wv2 = *(const float2*)(&wS[k * LDS_STRIDE + 2 * tx]);
            acc00 *= fmaf(-yv.x, wv2.x, 1.0f);
            acc01 *= fmaf(-yv.x, wv2.y, 1.0f);
            acc10 *= fmaf(-yv.y, wv2.x, 1.0f);
            acc11 *= fmaf(-yv.y, wv2.y, 1.0f);
        }

        __syncthreads();
    }

    const int r0 = bBase + 2 * ty;
    const int c0 = oBase + 2 * tx;
    *(float2*)(&out[r0 * DIM_O + c0]) = make_float2(acc00, acc01);
    *(float2*)(&out[(r0 + 1) * DIM_O + c0]) = make_float2(acc10, acc11);
}

extern "C" void kernel_launch(void* const* d_in, const int* in_sizes, int n_in,
                              void* d_out, int out_size, void* d_ws, size_t ws_size,
                              hipStream_t stream) {
    const float* x = (const float*)d_in[0];   // [2048, 512]
    const float* w = (const float*)d_in[1];   // [512, 256]
    const float* qz = (const float*)d_in[2];  // [512]
    float* out = (float*)d_out;               // [2048, 256]

    dim3 grid(DIM_B / TILE_B, DIM_O / TILE_O);  // (64, 8) = 512 blocks
    dim3 block(256);
    l0conj_kernel<<<grid, block, 0, stream>>>(x, w, qz, out);
}